// Round 12
// baseline (6085.511 us; speedup 1.0000x reference)
//
#include <hip/hip_runtime.h>
#include <stdint.h>

namespace {

constexpr int B_   = 512;
constexpr int T_   = 512;
constexpr int IN_  = 6;
constexpr int H_   = 64;
constexpr int HH_  = 128;
constexpr int OUT_ = 8;

typedef _Float16 f16x2 __attribute__((ext_vector_type(2)));

__device__ __forceinline__ float dot2f(uint32_t w, uint32_t z, float acc) {
    return __builtin_amdgcn_fdot2(__builtin_bit_cast(f16x2, w),
                                  __builtin_bit_cast(f16x2, z), acc, false);
}

__device__ __forceinline__ uint32_t pack2f(float a, float b) {
    f16x2 p;
    p[0] = (_Float16)a;
    p[1] = (_Float16)b;
    return __builtin_bit_cast(uint32_t, p);
}

// DPP lane-xor adds (pure VALU, no LDS pipe):
__device__ __forceinline__ float pxor1(float v) {   // quad_perm [1,0,3,2]
    int y = __builtin_amdgcn_mov_dpp(__builtin_bit_cast(int, v), 0xB1, 0xF, 0xF, true);
    return v + __builtin_bit_cast(float, y);
}
__device__ __forceinline__ float pxor2(float v) {   // quad_perm [2,3,0,1]
    int y = __builtin_amdgcn_mov_dpp(__builtin_bit_cast(int, v), 0x4E, 0xF, 0xF, true);
    return v + __builtin_bit_cast(float, y);
}
__device__ __forceinline__ float pxor8(float v) {   // row_ror:8 == xor8 within row16
    int y = __builtin_amdgcn_mov_dpp(__builtin_bit_cast(int, v), 0x128, 0xF, 0xF, true);
    return v + __builtin_bit_cast(float, y);
}
// full sum over the 8 k-octant lanes (octant id on lane bits {0,1,3})
__device__ __forceinline__ float qsum8(float v) {
    return pxor8(pxor2(pxor1(v)));
}

__device__ __forceinline__ float tanh_fast(float v) {
    float ax = fabsf(v);
    float e  = __expf(2.0f * ax);
    float r  = 1.0f - 2.0f / (e + 1.0f);
    return copysignf(r, v);
}

// One workgroup (1024 threads) per ONE batch element, grid 512 (2 rounds).
// Weights: 45056 packed-f16-pair u32 / 1024 threads = 44 u32/thread -> VGPR
// target 64 -> 4 waves/SIMD (16 waves/CU), double the 8-wave ceiling of all
// prior rounds (occupancy law: waves/SIMD = 512/(2*VGPR)).
// Lane-bit layout (t = 10 bits): k-octant = bits{0,1,3} (DPP-reducible:
// xor1, xor2, xor8=row_ror:8); row-pair rp = bit5 (xor32 via shfl); z-column
// zcol = rp | bit2<<1 | bit4<<2 | (t>>6)<<3  (128 columns).
// W_out cols {3z,3z+1,3z+2} -> A-row zcol>>1, dims rp*3+{0,1,2}.
__global__ __launch_bounds__(1024, 1) void cde_kernel(
    const float* __restrict__ x,
    const float* __restrict__ W_init, const float* __restrict__ b_init,
    const float* __restrict__ W_in,   const float* __restrict__ b_in,
    const float* __restrict__ W_h1,   const float* __restrict__ b_h1,
    const float* __restrict__ W_h2,   const float* __restrict__ b_h2,
    const float* __restrict__ W_out,  const float* __restrict__ b_out,
    const float* __restrict__ W_fin,  const float* __restrict__ b_fin,
    float* __restrict__ out)
{
    const int t    = threadIdx.x;
    const int koct = (t & 3) | ((t >> 1) & 4);                 // bits 0,1,3
    const int rp   = (t >> 5) & 1;                             // bit 5
    const int zcol = rp | (((t >> 2) & 1) << 1) | (((t >> 4) & 1) << 2) | ((t >> 6) << 3);
    const int b    = blockIdx.x;

    __shared__ alignas(16) uint32_t hinu[H_ / 2];   // h as f16 (64)
    __shared__ alignas(16) uint32_t zAu[HH_ / 2];   // activation ping (128 f16)
    __shared__ alignas(16) uint32_t zBu[HH_ / 2];   // activation pong
    __shared__ float dxs[IN_];
    __shared__ float hbuf[H_];
    __shared__ float wfin_s[H_ * 9];                // padded [r][9]: spread banks
    __shared__ float bfin_s[OUT_];

    // ---- register-resident f16 weights: 4+8+8+24 = 44 u32 (k-octant slice) ----
    uint32_t w1[4], w2[8], w3[8], w4[24];
    #pragma unroll
    for (int i = 0; i < 4; ++i) {
        int k = koct * 8 + 2 * i;
        w1[i] = pack2f(W_in[k * HH_ + zcol], W_in[(k + 1) * HH_ + zcol]);
    }
    #pragma unroll
    for (int i = 0; i < 8; ++i) {
        int k = koct * 16 + 2 * i;
        w2[i] = pack2f(W_h1[k * HH_ + zcol], W_h1[(k + 1) * HH_ + zcol]);
        w3[i] = pack2f(W_h2[k * HH_ + zcol], W_h2[(k + 1) * HH_ + zcol]);
    }
    #pragma unroll
    for (int j = 0; j < 3; ++j) {
        const int col = 3 * zcol + j;
        #pragma unroll
        for (int i = 0; i < 8; ++i) {
            int k = koct * 16 + 2 * i;
            w4[j * 8 + i] = pack2f(W_out[k * 384 + col], W_out[(k + 1) * 384 + col]);
        }
    }
    const float bin_r = b_in[zcol];
    const float bh1_r = b_h1[zcol];
    const float bh2_r = b_h2[zcol];
    const float bo0 = b_out[3 * zcol], bo1 = b_out[3 * zcol + 1], bo2 = b_out[3 * zcol + 2];
    const int   r_own = zcol >> 1;                   // h-row of this thread's group
    const bool  wr_z  = (koct == 0);                 // z writers (128 lanes)
    const bool  wr_h  = (koct == 0) && (rp == 0);    // h writers (64 lanes)

    // W_fin -> padded LDS (conflict-spread); b_fin -> LDS
    for (int i = t; i < H_ * OUT_; i += 1024)
        wfin_s[(i >> 3) * 9 + (i & 7)] = W_fin[i];
    if (t < OUT_) bfin_s[t] = b_fin[t];

    const size_t xbase = (size_t)b * T_ * IN_;
    const size_t obase = (size_t)b * T_ * OUT_;

    // dX producer: threads 0..5
    float xa = 0.f, xb = 0.f;
    if (t < IN_) {
        xa = x[xbase + t];
        xb = x[xbase + IN_ + t];
        dxs[t] = xb - xa;                 // dX for step 0
        xa = xb;
        xb = x[xbase + 2 * IN_ + t];
    }

    // ---- h0 (threads t<64) ----
    if (t < H_) {
        float s = b_init[t];
        #pragma unroll
        for (int i = 0; i < IN_; ++i) s += x[xbase + i] * W_init[i * H_ + t];
        hbuf[t] = s;
        ((_Float16*)hinu)[t] = (_Float16)s;
    }
    __syncthreads();

    // RK4 state (redundant in the 16 lanes of each row group)
    float h_reg = hbuf[r_own];
    float hacc  = 0.f;

#define OUT_STAGE(TT)                                                          \
    if (t < 64) {                                                              \
        int o_ = t & 7, part_ = t >> 3;                                        \
        float s_ = 0.f;                                                        \
        _Pragma("unroll")                                                      \
        for (int j = 0; j < 8; ++j)                                            \
            s_ += hbuf[part_ * 8 + j] * wfin_s[(part_ * 8 + j) * 9 + o_];      \
        s_ += __shfl_xor(s_, 8);                                               \
        s_ += __shfl_xor(s_, 16);                                              \
        s_ += __shfl_xor(s_, 32);                                              \
        if (part_ == 0)                                                        \
            out[obase + (size_t)(TT) * OUT_ + o_] = s_ + bfin_s[o_];           \
    }

    OUT_STAGE(0)

    float dxr[3];

    for (int step = 0; step < T_ - 1; ++step) {
        #pragma unroll
        for (int s4 = 0; s4 < 4; ++s4) {
            // ---- phase 1: (dxr reload + out-stage on s4==0) + G1: h -> z1 ----
            if (s4 == 0) {
                #pragma unroll
                for (int j = 0; j < 3; ++j) dxr[j] = dxs[rp * 3 + j];
                if (step > 0) { OUT_STAGE(step) }
            }
            {
                uint4 hq = *reinterpret_cast<const uint4*>(hinu + koct * 4);
                float a = 0.f, d = 0.f;
                a = dot2f(w1[0], hq.x, a); d = dot2f(w1[1], hq.y, d);
                a = dot2f(w1[2], hq.z, a); d = dot2f(w1[3], hq.w, d);
                float z = fmaxf(bin_r + qsum8(a + d), 0.f);
                if (wr_z) ((_Float16*)zAu)[zcol] = (_Float16)z;
            }
            __syncthreads();

            // ---- phase 2: G2 zA -> zB ----
            {
                uint4 q0 = *reinterpret_cast<const uint4*>(zAu + koct * 8);
                uint4 q1 = *reinterpret_cast<const uint4*>(zAu + koct * 8 + 4);
                float a = 0.f, d = 0.f;
                a = dot2f(w2[0], q0.x, a); d = dot2f(w2[1], q0.y, d);
                a = dot2f(w2[2], q0.z, a); d = dot2f(w2[3], q0.w, d);
                a = dot2f(w2[4], q1.x, a); d = dot2f(w2[5], q1.y, d);
                a = dot2f(w2[6], q1.z, a); d = dot2f(w2[7], q1.w, d);
                float z = fmaxf(bh1_r + qsum8(a + d), 0.f);
                if (wr_z) ((_Float16*)zBu)[zcol] = (_Float16)z;
            }
            __syncthreads();

            // ---- phase 3: G3 zB -> zA ----
            {
                uint4 q0 = *reinterpret_cast<const uint4*>(zBu + koct * 8);
                uint4 q1 = *reinterpret_cast<const uint4*>(zBu + koct * 8 + 4);
                float a = 0.f, d = 0.f;
                a = dot2f(w3[0], q0.x, a); d = dot2f(w3[1], q0.y, d);
                a = dot2f(w3[2], q0.z, a); d = dot2f(w3[3], q0.w, d);
                a = dot2f(w3[4], q1.x, a); d = dot2f(w3[5], q1.y, d);
                a = dot2f(w3[6], q1.z, a); d = dot2f(w3[7], q1.w, d);
                float z = fmaxf(bh2_r + qsum8(a + d), 0.f);
                if (wr_z) ((_Float16*)zAu)[zcol] = (_Float16)z;
            }
            __syncthreads();

            // ---- phase 4: G4 (3 A-cols) + in-register einsum + RK4 ----
            {
                uint4 q0 = *reinterpret_cast<const uint4*>(zAu + koct * 8);
                uint4 q1 = *reinterpret_cast<const uint4*>(zAu + koct * 8 + 4);
                float av0 = 0.f, av1 = 0.f, av2 = 0.f;
                av0 = dot2f(w4[0],  q0.x, av0); av0 = dot2f(w4[1],  q0.y, av0);
                av0 = dot2f(w4[2],  q0.z, av0); av0 = dot2f(w4[3],  q0.w, av0);
                av0 = dot2f(w4[4],  q1.x, av0); av0 = dot2f(w4[5],  q1.y, av0);
                av0 = dot2f(w4[6],  q1.z, av0); av0 = dot2f(w4[7],  q1.w, av0);
                av1 = dot2f(w4[8],  q0.x, av1); av1 = dot2f(w4[9],  q0.y, av1);
                av1 = dot2f(w4[10], q0.z, av1); av1 = dot2f(w4[11], q0.w, av1);
                av1 = dot2f(w4[12], q1.x, av1); av1 = dot2f(w4[13], q1.y, av1);
                av1 = dot2f(w4[14], q1.z, av1); av1 = dot2f(w4[15], q1.w, av1);
                av2 = dot2f(w4[16], q0.x, av2); av2 = dot2f(w4[17], q0.y, av2);
                av2 = dot2f(w4[18], q0.z, av2); av2 = dot2f(w4[19], q0.w, av2);
                av2 = dot2f(w4[20], q1.x, av2); av2 = dot2f(w4[21], q1.y, av2);
                av2 = dot2f(w4[22], q1.z, av2); av2 = dot2f(w4[23], q1.w, av2);
                av0 = qsum8(av0); av1 = qsum8(av1); av2 = qsum8(av2);
                float kvp = tanh_fast(bo0 + av0) * dxr[0]
                          + tanh_fast(bo1 + av1) * dxr[1]
                          + tanh_fast(bo2 + av2) * dxr[2];
                float kv = kvp + __shfl_xor(kvp, 32);   // row pair (zcol, zcol^1)

                hacc += ((s4 == 1 || s4 == 2) ? 2.0f : 1.0f) * kv;
                float hs;
                if (s4 < 3) {
                    hs = h_reg + ((s4 == 2) ? 1.0f : 0.5f) * kv;
                } else {
                    h_reg += hacc * (1.0f / 6.0f);
                    hacc = 0.f;
                    hs = h_reg;
                }
                if (wr_h) {
                    ((_Float16*)hinu)[r_own] = (_Float16)hs;
                    if (s4 == 3) hbuf[r_own] = h_reg;
                }
            }
            // dX for step+1 (read at next step's s4==0, after the barrier below)
            if (s4 == 3 && step + 2 < T_ && t < IN_) {
                dxs[t] = xb - xa;
                xa = xb;
                if (step + 3 < T_) xb = x[xbase + (size_t)(step + 3) * IN_ + t];
            }
            __syncthreads();
        }
    }

    OUT_STAGE(T_ - 1)
#undef OUT_STAGE
}

} // namespace

extern "C" void kernel_launch(void* const* d_in, const int* in_sizes, int n_in,
                              void* d_out, int out_size, void* d_ws, size_t ws_size,
                              hipStream_t stream) {
    const float* x      = (const float*)d_in[0];
    const float* W_init = (const float*)d_in[1];
    const float* b_init = (const float*)d_in[2];
    const float* W_in   = (const float*)d_in[3];
    const float* b_in   = (const float*)d_in[4];
    const float* W_h1   = (const float*)d_in[5];
    const float* b_h1   = (const float*)d_in[6];
    const float* W_h2   = (const float*)d_in[7];
    const float* b_h2   = (const float*)d_in[8];
    const float* W_out  = (const float*)d_in[9];
    const float* b_out  = (const float*)d_in[10];
    const float* W_fin  = (const float*)d_in[11];
    const float* b_fin  = (const float*)d_in[12];
    float* out = (float*)d_out;

    cde_kernel<<<dim3(B_), dim3(1024), 0, stream>>>(
        x, W_init, b_init, W_in, b_in, W_h1, b_h1, W_h2, b_h2,
        W_out, b_out, W_fin, b_fin, out);
}

// Round 14
// 4808.739 us; speedup vs baseline: 1.2655x; 1.2655x over previous
//
#include <hip/hip_runtime.h>
#include <stdint.h>

// gfx950 unified VGPR/AGPR file: the compiler mirrors the AGPR budget to the
// VGPR count (accum_offset = vgpr), charging 2x registers of occupancy even
// for kernels that never touch AGPRs (R3..R12 evidence: waves/SIMD =
// 512/(2*VGPR)). Request a zero AGPR allocation if the toolchain exposes it.
#if defined(__has_attribute)
#if __has_attribute(amdgpu_agpr_alloc)
#define AGPR0 __attribute__((amdgpu_agpr_alloc(0)))
#elif __has_attribute(amdgpu_num_agpr)
#define AGPR0 __attribute__((amdgpu_num_agpr(0)))
#else
#define AGPR0
#endif
#else
#define AGPR0
#endif

namespace {

constexpr int B_   = 512;
constexpr int T_   = 512;
constexpr int IN_  = 6;
constexpr int H_   = 64;
constexpr int HH_  = 128;
constexpr int OUT_ = 8;

typedef _Float16 f16x2 __attribute__((ext_vector_type(2)));

__device__ __forceinline__ float dot2f(uint32_t w, uint32_t z, float acc) {
    return __builtin_amdgcn_fdot2(__builtin_bit_cast(f16x2, w),
                                  __builtin_bit_cast(f16x2, z), acc, false);
}

__device__ __forceinline__ uint32_t pack2f(float a, float b) {
    f16x2 p;
    p[0] = (_Float16)a;
    p[1] = (_Float16)b;
    return __builtin_bit_cast(uint32_t, p);
}

// sum across a 4-lane quad (kq = lane&3) via DPP quad_perm — pure VALU.
__device__ __forceinline__ float qsum4(float v) {
    int y = __builtin_amdgcn_mov_dpp(__builtin_bit_cast(int, v), 0xB1, 0xF, 0xF, true); // xor1
    v += __builtin_bit_cast(float, y);
    y = __builtin_amdgcn_mov_dpp(__builtin_bit_cast(int, v), 0x4E, 0xF, 0xF, true);     // xor2
    return v + __builtin_bit_cast(float, y);
}

__device__ __forceinline__ float tanh_fast(float v) {
    float ax = fabsf(v);
    float e  = __expf(2.0f * ax);
    float r  = 1.0f - 2.0f / (e + 1.0f);
    return copysignf(r, v);
}

// One workgroup (512 threads) per ONE batch element, grid 512.
// With AGPR0 honored: alloc = ~108 VGPR + 0 AGPR -> 2 blocks/CU co-resident
// (4 waves/SIMD, 16 waves/CU) with independently-interleaving barriers.
// Without it: exact R10 behavior (1 block/CU, 24% occ).
// Thread t: col c = t>>2 (one z-column), k-quarter kq = t&3 -> weights
// 88 u32/thread, zero duplication. W_out cols {3c,3c+1,3c+2} -> A-row c>>1,
// dims (c&1)*3+{0,1,2}; row summed via __shfl_xor(4). RK4 state maintained
// in all lanes, written by (kq==0 && c even) lanes (64 writers = 64 h-rows).
__global__ AGPR0 __launch_bounds__(512, 2) void cde_kernel(
    const float* __restrict__ x,
    const float* __restrict__ W_init, const float* __restrict__ b_init,
    const float* __restrict__ W_in,   const float* __restrict__ b_in,
    const float* __restrict__ W_h1,   const float* __restrict__ b_h1,
    const float* __restrict__ W_h2,   const float* __restrict__ b_h2,
    const float* __restrict__ W_out,  const float* __restrict__ b_out,
    const float* __restrict__ W_fin,  const float* __restrict__ b_fin,
    float* __restrict__ out)
{
    const int t  = threadIdx.x;
    const int c  = t >> 2;      // 0..127 (z-column)
    const int kq = t & 3;       // k-quarter
    const int b  = blockIdx.x;

    __shared__ alignas(16) uint32_t hinu[H_ / 2];   // h as f16
    __shared__ alignas(16) uint32_t zAu[HH_ / 2];   // activation ping
    __shared__ alignas(16) uint32_t zBu[HH_ / 2];   // activation pong
    __shared__ float dxs[IN_];
    __shared__ float hbuf[H_];

    // ---- register-resident f16 weights: 8+16+16+48 = 88 u32, no duplication ----
    uint32_t w1[8], w2[16], w3[16], w4[48];
    #pragma unroll
    for (int i = 0; i < 8; ++i) {
        int k = kq * 16 + 2 * i;
        w1[i] = pack2f(W_in[k * HH_ + c], W_in[(k + 1) * HH_ + c]);
    }
    #pragma unroll
    for (int i = 0; i < 16; ++i) {
        int k = kq * 32 + 2 * i;
        w2[i] = pack2f(W_h1[k * HH_ + c], W_h1[(k + 1) * HH_ + c]);
        w3[i] = pack2f(W_h2[k * HH_ + c], W_h2[(k + 1) * HH_ + c]);
    }
    #pragma unroll
    for (int j = 0; j < 3; ++j) {
        const int col = 3 * c + j;
        #pragma unroll
        for (int i = 0; i < 16; ++i) {
            int k = kq * 32 + 2 * i;
            w4[j * 16 + i] = pack2f(W_out[k * 384 + col], W_out[(k + 1) * 384 + col]);
        }
    }
    const float bin_r = b_in[c];
    const float bh1_r = b_h1[c];
    const float bh2_r = b_h2[c];
    float bo[3];
    #pragma unroll
    for (int j = 0; j < 3; ++j) bo[j] = b_out[3 * c + j];
    const int  dbase = (c & 1) * 3;   // dim offset of this thread's 3 A-cols
    const int  r_own = c >> 1;        // h-row this thread's pair reduces
    const bool wrt   = (kq == 0) && ((c & 1) == 0);   // state writer lanes
    const float bfin_r = (t < 64) ? b_fin[t & 7] : 0.0f;

    float wfr[8];
    #pragma unroll
    for (int j = 0; j < 8; ++j)
        wfr[j] = (t < 64) ? W_fin[((t >> 3) * 8 + j) * OUT_ + (t & 7)] : 0.0f;

    const size_t xbase = (size_t)b * T_ * IN_;
    const size_t obase = (size_t)b * T_ * OUT_;

    // dX producer: threads 0..5
    float xa = 0.f, xb = 0.f;
    if (t < IN_) {
        xa = x[xbase + t];
        xb = x[xbase + IN_ + t];
        dxs[t] = xb - xa;                 // dX for step 0
        xa = xb;
        xb = x[xbase + 2 * IN_ + t];
    }

    // ---- h0 (threads t<64) ----
    if (t < H_) {
        float s = b_init[t];
        #pragma unroll
        for (int i = 0; i < IN_; ++i) s += x[xbase + i] * W_init[i * H_ + t];
        hbuf[t] = s;
        ((_Float16*)hinu)[t] = (_Float16)s;
    }
    __syncthreads();

    // RK4 state (maintained redundantly in all lanes of the row pair)
    float h_reg = hbuf[r_own];
    float hacc  = 0.f;

#define OUT_STAGE(TT)                                                          \
    if (t < 64) {                                                              \
        int o_ = t & 7, part_ = t >> 3;                                        \
        float s_ = 0.f;                                                        \
        _Pragma("unroll")                                                      \
        for (int j = 0; j < 8; ++j) s_ += hbuf[part_ * 8 + j] * wfr[j];        \
        s_ += __shfl_xor(s_, 8);                                               \
        s_ += __shfl_xor(s_, 16);                                              \
        s_ += __shfl_xor(s_, 32);                                              \
        if (part_ == 0)                                                        \
            out[obase + (size_t)(TT) * OUT_ + o_] = s_ + bfin_r;               \
    }

    OUT_STAGE(0)

    float dxr[3];

    for (int step = 0; step < T_ - 1; ++step) {
        #pragma unroll
        for (int s4 = 0; s4 < 4; ++s4) {
            // ---- phase 1: (dx reload + out-stage on s4==0) + G1: h -> z1 ----
            if (s4 == 0) {
                #pragma unroll
                for (int j = 0; j < 3; ++j) dxr[j] = dxs[dbase + j];
                if (step > 0) { OUT_STAGE(step) }
            }
            {
                const uint32_t* hp = hinu + kq * 8;
                uint4 q0 = *reinterpret_cast<const uint4*>(hp);
                uint4 q1 = *reinterpret_cast<const uint4*>(hp + 4);
                float a = 0.f, d = 0.f;
                a = dot2f(w1[0], q0.x, a); d = dot2f(w1[1], q0.y, d);
                a = dot2f(w1[2], q0.z, a); d = dot2f(w1[3], q0.w, d);
                a = dot2f(w1[4], q1.x, a); d = dot2f(w1[5], q1.y, d);
                a = dot2f(w1[6], q1.z, a); d = dot2f(w1[7], q1.w, d);
                float z = fmaxf(bin_r + qsum4(a + d), 0.f);
                if (kq == 0) ((_Float16*)zAu)[c] = (_Float16)z;
            }
            __syncthreads();

            // ---- phase 2: G2 zA -> zB ----
            {
                const uint32_t* zp = zAu + kq * 16;
                uint4 q0 = *reinterpret_cast<const uint4*>(zp);
                uint4 q1 = *reinterpret_cast<const uint4*>(zp + 4);
                uint4 q2 = *reinterpret_cast<const uint4*>(zp + 8);
                uint4 q3 = *reinterpret_cast<const uint4*>(zp + 12);
                float a = 0.f, d = 0.f;
                #pragma unroll
                for (int m = 0; m < 4; ++m) {
                    a = dot2f(w2[m],      (&q0.x)[m], a);
                    d = dot2f(w2[4 + m],  (&q1.x)[m], d);
                    a = dot2f(w2[8 + m],  (&q2.x)[m], a);
                    d = dot2f(w2[12 + m], (&q3.x)[m], d);
                }
                float z = fmaxf(bh1_r + qsum4(a + d), 0.f);
                if (kq == 0) ((_Float16*)zBu)[c] = (_Float16)z;
            }
            __syncthreads();

            // ---- phase 3: G3 zB -> zA ----
            {
                const uint32_t* zp = zBu + kq * 16;
                uint4 q0 = *reinterpret_cast<const uint4*>(zp);
                uint4 q1 = *reinterpret_cast<const uint4*>(zp + 4);
                uint4 q2 = *reinterpret_cast<const uint4*>(zp + 8);
                uint4 q3 = *reinterpret_cast<const uint4*>(zp + 12);
                float a = 0.f, d = 0.f;
                #pragma unroll
                for (int m = 0; m < 4; ++m) {
                    a = dot2f(w3[m],      (&q0.x)[m], a);
                    d = dot2f(w3[4 + m],  (&q1.x)[m], d);
                    a = dot2f(w3[8 + m],  (&q2.x)[m], a);
                    d = dot2f(w3[12 + m], (&q3.x)[m], d);
                }
                float z = fmaxf(bh2_r + qsum4(a + d), 0.f);
                if (kq == 0) ((_Float16*)zAu)[c] = (_Float16)z;
            }
            __syncthreads();

            // ---- phase 4: G4 (3 A-cols) + pair-sum einsum + RK4 ----
            {
                const uint32_t* zp = zAu + kq * 16;
                uint4 q0 = *reinterpret_cast<const uint4*>(zp);
                uint4 q1 = *reinterpret_cast<const uint4*>(zp + 4);
                uint4 q2 = *reinterpret_cast<const uint4*>(zp + 8);
                uint4 q3 = *reinterpret_cast<const uint4*>(zp + 12);
                float av0 = 0.f, av1 = 0.f, av2 = 0.f;
                #pragma unroll
                for (int m = 0; m < 4; ++m) {
                    uint32_t z0 = (&q0.x)[m], z1 = (&q1.x)[m], z2 = (&q2.x)[m], z3 = (&q3.x)[m];
                    av0 = dot2f(w4[m],      z0, av0); av0 = dot2f(w4[4 + m],  z1, av0);
                    av0 = dot2f(w4[8 + m],  z2, av0); av0 = dot2f(w4[12 + m], z3, av0);
                    av1 = dot2f(w4[16 + m], z0, av1); av1 = dot2f(w4[20 + m], z1, av1);
                    av1 = dot2f(w4[24 + m], z2, av1); av1 = dot2f(w4[28 + m], z3, av1);
                    av2 = dot2f(w4[32 + m], z0, av2); av2 = dot2f(w4[36 + m], z1, av2);
                    av2 = dot2f(w4[40 + m], z2, av2); av2 = dot2f(w4[44 + m], z3, av2);
                }
                av0 = qsum4(av0); av1 = qsum4(av1); av2 = qsum4(av2);
                float kvp = tanh_fast(bo[0] + av0) * dxr[0]
                          + tanh_fast(bo[1] + av1) * dxr[1]
                          + tanh_fast(bo[2] + av2) * dxr[2];
                float kv = kvp + __shfl_xor(kvp, 4);   // pair (c, c^1) -> full row sum

                hacc += ((s4 == 1 || s4 == 2) ? 2.0f : 1.0f) * kv;
                float hs;
                if (s4 < 3) {
                    hs = h_reg + ((s4 == 2) ? 1.0f : 0.5f) * kv;
                } else {
                    h_reg += hacc * (1.0f / 6.0f);
                    hacc = 0.f;
                    hs = h_reg;
                }
                if (wrt) {
                    ((_Float16*)hinu)[r_own] = (_Float16)hs;
                    if (s4 == 3) hbuf[r_own] = h_reg;
                }
            }
            // dX for step+1 (read at next step's s4==0, after the barrier below)
            if (s4 == 3 && step + 2 < T_ && t < IN_) {
                dxs[t] = xb - xa;
                xa = xb;
                if (step + 3 < T_) xb = x[xbase + (size_t)(step + 3) * IN_ + t];
            }
            __syncthreads();
        }
    }

    OUT_STAGE(T_ - 1)
#undef OUT_STAGE
}

} // namespace

extern "C" void kernel_launch(void* const* d_in, const int* in_sizes, int n_in,
                              void* d_out, int out_size, void* d_ws, size_t ws_size,
                              hipStream_t stream) {
    const float* x      = (const float*)d_in[0];
    const float* W_init = (const float*)d_in[1];
    const float* b_init = (const float*)d_in[2];
    const float* W_in   = (const float*)d_in[3];
    const float* b_in   = (const float*)d_in[4];
    const float* W_h1   = (const float*)d_in[5];
    const float* b_h1   = (const float*)d_in[6];
    const float* W_h2   = (const float*)d_in[7];
    const float* b_h2   = (const float*)d_in[8];
    const float* W_out  = (const float*)d_in[9];
    const float* b_out  = (const float*)d_in[10];
    const float* W_fin  = (const float*)d_in[11];
    const float* b_fin  = (const float*)d_in[12];
    float* out = (float*)d_out;

    cde_kernel<<<dim3(B_), dim3(512), 0, stream>>>(
        x, W_init, b_init, W_in, b_in, W_h1, b_h1, W_h2, b_h2,
        W_out, b_out, W_fin, b_fin, out);
}

// Round 15
// 3451.588 us; speedup vs baseline: 1.7631x; 1.3932x over previous
//
#include <hip/hip_runtime.h>
#include <stdint.h>

#if defined(__has_attribute)
#if __has_attribute(amdgpu_agpr_alloc)
#define AGPR0 __attribute__((amdgpu_agpr_alloc(0)))
#else
#define AGPR0
#endif
#else
#define AGPR0
#endif

namespace {

constexpr int B_   = 512;
constexpr int T_   = 512;
constexpr int IN_  = 6;
constexpr int H_   = 64;
constexpr int HH_  = 128;
constexpr int OUT_ = 8;

// Padded weight-table geometry: [kh][c][kp], kp padded 32->36 u32 (16B-aligned
// rows, bank rotation 4c), kh offset +16 u32 (bank rotation between halves).
constexpr int WROW = 36;
constexpr int WOFF = HH_ * WROW + 16;   // 4624
constexpr int WSZ  = WOFF + HH_ * WROW; // 9232 u32 = 36.9 KB

typedef _Float16 f16x2 __attribute__((ext_vector_type(2)));

__device__ __forceinline__ float dot2f(uint32_t w, uint32_t z, float acc) {
    return __builtin_amdgcn_fdot2(__builtin_bit_cast(f16x2, w),
                                  __builtin_bit_cast(f16x2, z), acc, false);
}

__device__ __forceinline__ uint32_t pack2f(float a, float b) {
    f16x2 p;
    p[0] = (_Float16)a;
    p[1] = (_Float16)b;
    return __builtin_bit_cast(uint32_t, p);
}

// pair sum across kh lanes (t ^ 1) via DPP quad_perm [1,0,3,2] — pure VALU.
__device__ __forceinline__ float pxor1(float v) {
    int y = __builtin_amdgcn_mov_dpp(__builtin_bit_cast(int, v), 0xB1, 0xF, 0xF, true);
    return v + __builtin_bit_cast(float, y);
}
// pair sum across c-parity lanes (t ^ 2) via DPP quad_perm [2,3,0,1].
__device__ __forceinline__ float pxor2(float v) {
    int y = __builtin_amdgcn_mov_dpp(__builtin_bit_cast(int, v), 0x4E, 0xF, 0xF, true);
    return v + __builtin_bit_cast(float, y);
}

__device__ __forceinline__ float tanh_fast(float v) {
    float ax = fabsf(v);
    float e  = __expf(2.0f * ax);
    float r  = 1.0f - 2.0f / (e + 1.0f);
    return copysignf(r, v);
}

// One workgroup (256 threads) per ONE batch element, grid 512 -> 2 blocks/CU
// co-resident (mirror law: VGPR<=128), independent barriers interleave (the
// R11 mechanism). Register/LDS rebalance vs R11: regs hold only w1[16]+w4[96]
// (112 pinned, ~20 spill vs R11's ~80); W_h1/W_h2 live in padded bank-rotated
// LDS tables streamed as aligned b128; wfin/bfin in padded LDS.
// Thread t: z-col c = t>>1, k-half kh = t&1. W_out cols {3c,3c+1,3c+2} ->
// A-row c>>1, dims (c&1)*3+{0,1,2}; kh-reduce pxor1, row-reduce pxor2.
__global__ AGPR0 __launch_bounds__(256, 2) void cde_kernel(
    const float* __restrict__ x,
    const float* __restrict__ W_init, const float* __restrict__ b_init,
    const float* __restrict__ W_in,   const float* __restrict__ b_in,
    const float* __restrict__ W_h1,   const float* __restrict__ b_h1,
    const float* __restrict__ W_h2,   const float* __restrict__ b_h2,
    const float* __restrict__ W_out,  const float* __restrict__ b_out,
    const float* __restrict__ W_fin,  const float* __restrict__ b_fin,
    float* __restrict__ out)
{
    const int t  = threadIdx.x;
    const int c  = t >> 1;      // 0..127 (z-column)
    const int kh = t & 1;       // k-half
    const int b  = blockIdx.x;

    __shared__ alignas(16) uint32_t w2s[WSZ];       // W_h1 padded
    __shared__ alignas(16) uint32_t w3s[WSZ];       // W_h2 padded
    __shared__ alignas(16) uint32_t hinu[H_ / 2];   // h as f16
    __shared__ alignas(16) uint32_t zAu[HH_ / 2];   // activation ping
    __shared__ alignas(16) uint32_t zBu[HH_ / 2];   // activation pong
    __shared__ float dxs[IN_];
    __shared__ float hbuf[H_];
    __shared__ float wfin_s[H_ * 9];                // padded [r][9]
    __shared__ float bfin_s[OUT_];

    // ---- register-resident weights: w1[16] + w4[96] = 112 u32 ----
    uint32_t w1[16], w4[96];
    #pragma unroll
    for (int i = 0; i < 16; ++i) {
        int k = kh * 32 + 2 * i;
        w1[i] = pack2f(W_in[k * HH_ + c], W_in[(k + 1) * HH_ + c]);
    }
    #pragma unroll
    for (int j = 0; j < 3; ++j) {
        const int col = 3 * c + j;
        #pragma unroll
        for (int i = 0; i < 32; ++i) {
            int k = kh * 64 + 2 * i;
            w4[j * 32 + i] = pack2f(W_out[k * 384 + col], W_out[(k + 1) * 384 + col]);
        }
    }
    // ---- W_h1 / W_h2 -> padded LDS tables ----
    for (int i = t; i < 2 * HH_ * 32; i += 256) {   // 8192 entries each
        int khw = i >> 12;          // 0/1
        int rem = i & 4095;
        int kp  = rem >> 7;         // 0..31
        int cc  = rem & 127;
        int dst = khw * WOFF + cc * WROW + kp;
        int k   = khw * 64 + 2 * kp;
        w2s[dst] = pack2f(W_h1[k * HH_ + cc], W_h1[(k + 1) * HH_ + cc]);
        w3s[dst] = pack2f(W_h2[k * HH_ + cc], W_h2[(k + 1) * HH_ + cc]);
    }
    for (int i = t; i < H_ * OUT_; i += 256)
        wfin_s[(i >> 3) * 9 + (i & 7)] = W_fin[i];
    if (t < OUT_) bfin_s[t] = b_fin[t];

    const float bin_r = b_in[c];
    const float bh1_r = b_h1[c];
    const float bh2_r = b_h2[c];
    float bo[3];
    #pragma unroll
    for (int j = 0; j < 3; ++j) bo[j] = b_out[3 * c + j];
    const int  dbase = (c & 1) * 3;   // dX dims of this thread's 3 A-cols
    const int  r_own = c >> 1;        // h-row this thread's quad reduces
    const bool wrt   = (t & 3) == 0;  // state writer lanes (64 = 64 rows)

    const uint32_t* wp2 = w2s + kh * WOFF + c * WROW;
    const uint32_t* wp3 = w3s + kh * WOFF + c * WROW;

    const size_t xbase = (size_t)b * T_ * IN_;
    const size_t obase = (size_t)b * T_ * OUT_;

    // dX producer: threads 0..5
    float xa = 0.f, xb = 0.f;
    if (t < IN_) {
        xa = x[xbase + t];
        xb = x[xbase + IN_ + t];
        dxs[t] = xb - xa;                 // dX for step 0
        xa = xb;
        xb = x[xbase + 2 * IN_ + t];
    }

    // ---- h0 (threads t<64) ----
    if (t < H_) {
        float s = b_init[t];
        #pragma unroll
        for (int i = 0; i < IN_; ++i) s += x[xbase + i] * W_init[i * H_ + t];
        hbuf[t] = s;
        ((_Float16*)hinu)[t] = (_Float16)s;
    }
    __syncthreads();

    // RK4 state (redundant in all 4 lanes of each row quad)
    float h_reg = hbuf[r_own];
    float hacc  = 0.f;

#define OUT_STAGE(TT)                                                          \
    if (t < 64) {                                                              \
        int o_ = t & 7, part_ = t >> 3;                                        \
        float s_ = 0.f;                                                        \
        _Pragma("unroll")                                                      \
        for (int j = 0; j < 8; ++j)                                            \
            s_ += hbuf[part_ * 8 + j] * wfin_s[(part_ * 8 + j) * 9 + o_];      \
        s_ += __shfl_xor(s_, 8);                                               \
        s_ += __shfl_xor(s_, 16);                                              \
        s_ += __shfl_xor(s_, 32);                                              \
        if (part_ == 0)                                                        \
            out[obase + (size_t)(TT) * OUT_ + o_] = s_ + bfin_s[o_];           \
    }

    OUT_STAGE(0)

    float dxr[3];

    for (int step = 0; step < T_ - 1; ++step) {
        #pragma unroll
        for (int s4 = 0; s4 < 4; ++s4) {
            // ---- phase 1: (dxr reload + out-stage on s4==0) + G1: h -> z1 ----
            if (s4 == 0) {
                #pragma unroll
                for (int j = 0; j < 3; ++j) dxr[j] = dxs[dbase + j];
                if (step > 0) { OUT_STAGE(step) }
            }
            {
                const uint32_t* hp = hinu + kh * 16;
                uint4 q0 = *reinterpret_cast<const uint4*>(hp);
                uint4 q1 = *reinterpret_cast<const uint4*>(hp + 4);
                uint4 q2 = *reinterpret_cast<const uint4*>(hp + 8);
                uint4 q3 = *reinterpret_cast<const uint4*>(hp + 12);
                float a = 0.f, d = 0.f;
                #pragma unroll
                for (int m = 0; m < 4; ++m) {
                    a = dot2f(w1[m],      (&q0.x)[m], a);
                    d = dot2f(w1[4 + m],  (&q1.x)[m], d);
                    a = dot2f(w1[8 + m],  (&q2.x)[m], a);
                    d = dot2f(w1[12 + m], (&q3.x)[m], d);
                }
                float z = fmaxf(bin_r + pxor1(a + d), 0.f);
                if (kh == 0) ((_Float16*)zAu)[c] = (_Float16)z;
            }
            __syncthreads();

            // ---- phase 2: G2 zA -> zB (weights streamed from LDS) ----
            {
                const uint32_t* zp = zAu + kh * 32;
                uint4 z0 = *reinterpret_cast<const uint4*>(zp);
                uint4 z1 = *reinterpret_cast<const uint4*>(zp + 4);
                uint4 wa = *reinterpret_cast<const uint4*>(wp2);
                uint4 wb = *reinterpret_cast<const uint4*>(wp2 + 4);
                float a = 0.f, d = 0.f;
                #pragma unroll
                for (int m = 0; m < 4; ++m) {
                    a = dot2f((&wa.x)[m], (&z0.x)[m], a);
                    d = dot2f((&wb.x)[m], (&z1.x)[m], d);
                }
                uint4 z2 = *reinterpret_cast<const uint4*>(zp + 8);
                uint4 z3 = *reinterpret_cast<const uint4*>(zp + 12);
                uint4 wc = *reinterpret_cast<const uint4*>(wp2 + 8);
                uint4 wd = *reinterpret_cast<const uint4*>(wp2 + 12);
                #pragma unroll
                for (int m = 0; m < 4; ++m) {
                    a = dot2f((&wc.x)[m], (&z2.x)[m], a);
                    d = dot2f((&wd.x)[m], (&z3.x)[m], d);
                }
                uint4 z4 = *reinterpret_cast<const uint4*>(zp + 16);
                uint4 z5 = *reinterpret_cast<const uint4*>(zp + 20);
                uint4 we = *reinterpret_cast<const uint4*>(wp2 + 16);
                uint4 wf = *reinterpret_cast<const uint4*>(wp2 + 20);
                #pragma unroll
                for (int m = 0; m < 4; ++m) {
                    a = dot2f((&we.x)[m], (&z4.x)[m], a);
                    d = dot2f((&wf.x)[m], (&z5.x)[m], d);
                }
                uint4 z6 = *reinterpret_cast<const uint4*>(zp + 24);
                uint4 z7 = *reinterpret_cast<const uint4*>(zp + 28);
                uint4 wg = *reinterpret_cast<const uint4*>(wp2 + 24);
                uint4 wh = *reinterpret_cast<const uint4*>(wp2 + 28);
                #pragma unroll
                for (int m = 0; m < 4; ++m) {
                    a = dot2f((&wg.x)[m], (&z6.x)[m], a);
                    d = dot2f((&wh.x)[m], (&z7.x)[m], d);
                }
                float z = fmaxf(bh1_r + pxor1(a + d), 0.f);
                if (kh == 0) ((_Float16*)zBu)[c] = (_Float16)z;
            }
            __syncthreads();

            // ---- phase 3: G3 zB -> zA (weights streamed from LDS) ----
            {
                const uint32_t* zp = zBu + kh * 32;
                uint4 z0 = *reinterpret_cast<const uint4*>(zp);
                uint4 z1 = *reinterpret_cast<const uint4*>(zp + 4);
                uint4 wa = *reinterpret_cast<const uint4*>(wp3);
                uint4 wb = *reinterpret_cast<const uint4*>(wp3 + 4);
                float a = 0.f, d = 0.f;
                #pragma unroll
                for (int m = 0; m < 4; ++m) {
                    a = dot2f((&wa.x)[m], (&z0.x)[m], a);
                    d = dot2f((&wb.x)[m], (&z1.x)[m], d);
                }
                uint4 z2 = *reinterpret_cast<const uint4*>(zp + 8);
                uint4 z3 = *reinterpret_cast<const uint4*>(zp + 12);
                uint4 wc = *reinterpret_cast<const uint4*>(wp3 + 8);
                uint4 wd = *reinterpret_cast<const uint4*>(wp3 + 12);
                #pragma unroll
                for (int m = 0; m < 4; ++m) {
                    a = dot2f((&wc.x)[m], (&z2.x)[m], a);
                    d = dot2f((&wd.x)[m], (&z3.x)[m], d);
                }
                uint4 z4 = *reinterpret_cast<const uint4*>(zp + 16);
                uint4 z5 = *reinterpret_cast<const uint4*>(zp + 20);
                uint4 we = *reinterpret_cast<const uint4*>(wp3 + 16);
                uint4 wf = *reinterpret_cast<const uint4*>(wp3 + 20);
                #pragma unroll
                for (int m = 0; m < 4; ++m) {
                    a = dot2f((&we.x)[m], (&z4.x)[m], a);
                    d = dot2f((&wf.x)[m], (&z5.x)[m], d);
                }
                uint4 z6 = *reinterpret_cast<const uint4*>(zp + 24);
                uint4 z7 = *reinterpret_cast<const uint4*>(zp + 28);
                uint4 wg = *reinterpret_cast<const uint4*>(wp3 + 24);
                uint4 wh = *reinterpret_cast<const uint4*>(wp3 + 28);
                #pragma unroll
                for (int m = 0; m < 4; ++m) {
                    a = dot2f((&wg.x)[m], (&z6.x)[m], a);
                    d = dot2f((&wh.x)[m], (&z7.x)[m], d);
                }
                float z = fmaxf(bh2_r + pxor1(a + d), 0.f);
                if (kh == 0) ((_Float16*)zAu)[c] = (_Float16)z;
            }
            __syncthreads();

            // ---- phase 4: G4 (3 A-cols, w4 in regs) + einsum + RK4 ----
            {
                const uint32_t* zp = zAu + kh * 32;
                uint4 z0 = *reinterpret_cast<const uint4*>(zp);
                uint4 z1 = *reinterpret_cast<const uint4*>(zp + 4);
                uint4 z2 = *reinterpret_cast<const uint4*>(zp + 8);
                uint4 z3 = *reinterpret_cast<const uint4*>(zp + 12);
                float av0 = 0.f, av1 = 0.f, av2 = 0.f;
                #pragma unroll
                for (int m = 0; m < 4; ++m) {
                    uint32_t y0 = (&z0.x)[m], y1 = (&z1.x)[m], y2 = (&z2.x)[m], y3 = (&z3.x)[m];
                    av0 = dot2f(w4[m],      y0, av0); av0 = dot2f(w4[4 + m],  y1, av0);
                    av0 = dot2f(w4[8 + m],  y2, av0); av0 = dot2f(w4[12 + m], y3, av0);
                    av1 = dot2f(w4[32 + m],      y0, av1); av1 = dot2f(w4[36 + m], y1, av1);
                    av1 = dot2f(w4[40 + m],      y2, av1); av1 = dot2f(w4[44 + m], y3, av1);
                    av2 = dot2f(w4[64 + m],      y0, av2); av2 = dot2f(w4[68 + m], y1, av2);
                    av2 = dot2f(w4[72 + m],      y2, av2); av2 = dot2f(w4[76 + m], y3, av2);
                }
                uint4 z4 = *reinterpret_cast<const uint4*>(zp + 16);
                uint4 z5 = *reinterpret_cast<const uint4*>(zp + 20);
                uint4 z6 = *reinterpret_cast<const uint4*>(zp + 24);
                uint4 z7 = *reinterpret_cast<const uint4*>(zp + 28);
                #pragma unroll
                for (int m = 0; m < 4; ++m) {
                    uint32_t y4 = (&z4.x)[m], y5 = (&z5.x)[m], y6 = (&z6.x)[m], y7 = (&z7.x)[m];
                    av0 = dot2f(w4[16 + m], y4, av0); av0 = dot2f(w4[20 + m], y5, av0);
                    av0 = dot2f(w4[24 + m], y6, av0); av0 = dot2f(w4[28 + m], y7, av0);
                    av1 = dot2f(w4[48 + m], y4, av1); av1 = dot2f(w4[52 + m], y5, av1);
                    av1 = dot2f(w4[56 + m], y6, av1); av1 = dot2f(w4[60 + m], y7, av1);
                    av2 = dot2f(w4[80 + m], y4, av2); av2 = dot2f(w4[84 + m], y5, av2);
                    av2 = dot2f(w4[88 + m], y6, av2); av2 = dot2f(w4[92 + m], y7, av2);
                }
                av0 = pxor1(av0); av1 = pxor1(av1); av2 = pxor1(av2);
                float kvp = tanh_fast(bo[0] + av0) * dxr[0]
                          + tanh_fast(bo[1] + av1) * dxr[1]
                          + tanh_fast(bo[2] + av2) * dxr[2];
                float kv = pxor2(kvp);          // row pair (c, c^1) -> full row sum

                hacc += ((s4 == 1 || s4 == 2) ? 2.0f : 1.0f) * kv;
                float hs;
                if (s4 < 3) {
                    hs = h_reg + ((s4 == 2) ? 1.0f : 0.5f) * kv;
                } else {
                    h_reg += hacc * (1.0f / 6.0f);
                    hacc = 0.f;
                    hs = h_reg;
                }
                if (wrt) {
                    ((_Float16*)hinu)[r_own] = (_Float16)hs;
                    if (s4 == 3) hbuf[r_own] = h_reg;
                }
            }
            // dX for step+1 (read at next step's s4==0, after the barrier below)
            if (s4 == 3 && step + 2 < T_ && t < IN_) {
                dxs[t] = xb - xa;
                xa = xb;
                if (step + 3 < T_) xb = x[xbase + (size_t)(step + 3) * IN_ + t];
            }
            __syncthreads();
        }
    }

    OUT_STAGE(T_ - 1)
#undef OUT_STAGE
}

} // namespace

extern "C" void kernel_launch(void* const* d_in, const int* in_sizes, int n_in,
                              void* d_out, int out_size, void* d_ws, size_t ws_size,
                              hipStream_t stream) {
    const float* x      = (const float*)d_in[0];
    const float* W_init = (const float*)d_in[1];
    const float* b_init = (const float*)d_in[2];
    const float* W_in   = (const float*)d_in[3];
    const float* b_in   = (const float*)d_in[4];
    const float* W_h1   = (const float*)d_in[5];
    const float* b_h1   = (const float*)d_in[6];
    const float* W_h2   = (const float*)d_in[7];
    const float* b_h2   = (const float*)d_in[8];
    const float* W_out  = (const float*)d_in[9];
    const float* b_out  = (const float*)d_in[10];
    const float* W_fin  = (const float*)d_in[11];
    const float* b_fin  = (const float*)d_in[12];
    float* out = (float*)d_out;

    cde_kernel<<<dim3(B_), dim3(256), 0, stream>>>(
        x, W_init, b_init, W_in, b_in, W_h1, b_h1, W_h2, b_h2,
        W_out, b_out, W_fin, b_fin, out);
}

// Round 16
// 3274.765 us; speedup vs baseline: 1.8583x; 1.0540x over previous
//
#include <hip/hip_runtime.h>
#include <stdint.h>

namespace {

constexpr int B_   = 512;
constexpr int T_   = 512;
constexpr int IN_  = 6;
constexpr int H_   = 64;
constexpr int HH_  = 128;
constexpr int OUT_ = 8;

typedef _Float16 f16x2 __attribute__((ext_vector_type(2)));

__device__ __forceinline__ float dot2f(uint32_t w, uint32_t z, float acc) {
    return __builtin_amdgcn_fdot2(__builtin_bit_cast(f16x2, w),
                                  __builtin_bit_cast(f16x2, z), acc, false);
}

__device__ __forceinline__ uint32_t pack2f(float a, float b) {
    f16x2 p;
    p[0] = (_Float16)a;
    p[1] = (_Float16)b;
    return __builtin_bit_cast(uint32_t, p);
}

// pair sum across kh lanes (t ^ 1) via DPP quad_perm [1,0,3,2] — pure VALU.
__device__ __forceinline__ float pxor1(float v) {
    int y = __builtin_amdgcn_mov_dpp(__builtin_bit_cast(int, v), 0xB1, 0xF, 0xF, true);
    return v + __builtin_bit_cast(float, y);
}
// pair sum across c-parity lanes (t ^ 2) via DPP quad_perm [2,3,0,1].
__device__ __forceinline__ float pxor2(float v) {
    int y = __builtin_amdgcn_mov_dpp(__builtin_bit_cast(int, v), 0x4E, 0xF, 0xF, true);
    return v + __builtin_bit_cast(float, y);
}

__device__ __forceinline__ float tanh_fast(float v) {
    float ax = fabsf(v);
    float e  = __expf(2.0f * ax);
    float r  = 1.0f - 2.0f / (e + 1.0f);
    return copysignf(r, v);
}

// One workgroup (256 threads) per ONE batch element, grid 512 -> 2 blocks/CU
// co-resident (mirror law: VGPR<=128), independent barriers interleave.
// vs R15: weight tables are LANE-INTERLEAVED — chunk j of thread t at
// [(j*256+t)*4] u32 — so each wave's ds_read_b128 hits 64 consecutive 16B
// chunks (the m134 zero-conflict pattern). R15's row-major private rows gave
// 2.7e8 bank-conflict cycles; this layout is the fix.
// Thread t: z-col c = t>>1, k-half kh = t&1. w1[16]+w4[96] in regs;
// W_h1/W_h2 streamed from interleaved LDS; wfin/bfin in LDS (2-way reads).
__global__ __launch_bounds__(256, 2) void cde_kernel(
    const float* __restrict__ x,
    const float* __restrict__ W_init, const float* __restrict__ b_init,
    const float* __restrict__ W_in,   const float* __restrict__ b_in,
    const float* __restrict__ W_h1,   const float* __restrict__ b_h1,
    const float* __restrict__ W_h2,   const float* __restrict__ b_h2,
    const float* __restrict__ W_out,  const float* __restrict__ b_out,
    const float* __restrict__ W_fin,  const float* __restrict__ b_fin,
    float* __restrict__ out)
{
    const int t  = threadIdx.x;
    const int c  = t >> 1;      // 0..127 (z-column)
    const int kh = t & 1;       // k-half
    const int b  = blockIdx.x;

    __shared__ alignas(16) uint32_t w2s[8 * 256 * 4];   // W_h1 interleaved, 32KB
    __shared__ alignas(16) uint32_t w3s[8 * 256 * 4];   // W_h2 interleaved, 32KB
    __shared__ alignas(16) uint32_t hinu[H_ / 2];       // h as f16
    __shared__ alignas(16) uint32_t zAu[HH_ / 2];       // activation ping
    __shared__ alignas(16) uint32_t zBu[HH_ / 2];       // activation pong
    __shared__ float dxs[IN_];
    __shared__ float hbuf[H_];
    __shared__ float wfin_s[H_ * 9];                    // padded [r][9]
    __shared__ float bfin_s[OUT_];

    // ---- register-resident weights: w1[16] + w4[96] = 112 u32 ----
    uint32_t w1[16], w4[96];
    #pragma unroll
    for (int i = 0; i < 16; ++i) {
        int k = kh * 32 + 2 * i;
        w1[i] = pack2f(W_in[k * HH_ + c], W_in[(k + 1) * HH_ + c]);
    }
    #pragma unroll
    for (int j = 0; j < 3; ++j) {
        const int col = 3 * c + j;
        #pragma unroll
        for (int i = 0; i < 32; ++i) {
            int k = kh * 64 + 2 * i;
            w4[j * 32 + i] = pack2f(W_out[k * 384 + col], W_out[(k + 1) * 384 + col]);
        }
    }
    // ---- W_h1 / W_h2 -> lane-interleaved LDS tables ----
    // u32 index i: chunk = i>>2 (j = chunk>>8, owner thread tt = chunk&255),
    // m = i&3. Owner (cc=tt>>1, khw=tt&1) pair index p = j*4+m, k = khw*64+2p.
    for (int i = t; i < 8192; i += 256) {
        int m   = i & 3;
        int ch  = i >> 2;
        int j   = ch >> 8;
        int tt  = ch & 255;
        int cc  = tt >> 1;
        int khw = tt & 1;
        int k   = khw * 64 + 2 * (j * 4 + m);
        w2s[i] = pack2f(W_h1[k * HH_ + cc], W_h1[(k + 1) * HH_ + cc]);
        w3s[i] = pack2f(W_h2[k * HH_ + cc], W_h2[(k + 1) * HH_ + cc]);
    }
    for (int i = t; i < H_ * OUT_; i += 256)
        wfin_s[(i >> 3) * 9 + (i & 7)] = W_fin[i];
    if (t < OUT_) bfin_s[t] = b_fin[t];

    const float bin_r = b_in[c];
    const float bh1_r = b_h1[c];
    const float bh2_r = b_h2[c];
    float bo[3];
    #pragma unroll
    for (int j = 0; j < 3; ++j) bo[j] = b_out[3 * c + j];
    const int  dbase = (c & 1) * 3;   // dX dims of this thread's 3 A-cols
    const int  r_own = c >> 1;        // h-row this thread's quad reduces
    const bool wrt   = (t & 3) == 0;  // state writer lanes (64 = 64 rows)

    const size_t xbase = (size_t)b * T_ * IN_;
    const size_t obase = (size_t)b * T_ * OUT_;

    // dX producer: threads 0..5
    float xa = 0.f, xb = 0.f;
    if (t < IN_) {
        xa = x[xbase + t];
        xb = x[xbase + IN_ + t];
        dxs[t] = xb - xa;                 // dX for step 0
        xa = xb;
        xb = x[xbase + 2 * IN_ + t];
    }

    // ---- h0 (threads t<64) ----
    if (t < H_) {
        float s = b_init[t];
        #pragma unroll
        for (int i = 0; i < IN_; ++i) s += x[xbase + i] * W_init[i * H_ + t];
        hbuf[t] = s;
        ((_Float16*)hinu)[t] = (_Float16)s;
    }
    __syncthreads();

    // RK4 state (redundant in all 4 lanes of each row quad)
    float h_reg = hbuf[r_own];
    float hacc  = 0.f;

#define OUT_STAGE(TT)                                                          \
    if (t < 64) {                                                              \
        int o_ = t & 7, part_ = t >> 3;                                        \
        float s_ = 0.f;                                                        \
        _Pragma("unroll")                                                      \
        for (int j = 0; j < 8; ++j)                                            \
            s_ += hbuf[part_ * 8 + j] * wfin_s[(part_ * 8 + j) * 9 + o_];      \
        s_ += __shfl_xor(s_, 8);                                               \
        s_ += __shfl_xor(s_, 16);                                              \
        s_ += __shfl_xor(s_, 32);                                              \
        if (part_ == 0)                                                        \
            out[obase + (size_t)(TT) * OUT_ + o_] = s_ + bfin_s[o_];           \
    }

    OUT_STAGE(0)

    float dxr[3];

    for (int step = 0; step < T_ - 1; ++step) {
        #pragma unroll
        for (int s4 = 0; s4 < 4; ++s4) {
            // ---- phase 1: (dxr reload + out-stage on s4==0) + G1: h -> z1 ----
            if (s4 == 0) {
                #pragma unroll
                for (int j = 0; j < 3; ++j) dxr[j] = dxs[dbase + j];
                if (step > 0) { OUT_STAGE(step) }
            }
            {
                const uint32_t* hp = hinu + kh * 16;
                uint4 q0 = *reinterpret_cast<const uint4*>(hp);
                uint4 q1 = *reinterpret_cast<const uint4*>(hp + 4);
                uint4 q2 = *reinterpret_cast<const uint4*>(hp + 8);
                uint4 q3 = *reinterpret_cast<const uint4*>(hp + 12);
                float a = 0.f, d = 0.f;
                #pragma unroll
                for (int m = 0; m < 4; ++m) {
                    a = dot2f(w1[m],      (&q0.x)[m], a);
                    d = dot2f(w1[4 + m],  (&q1.x)[m], d);
                    a = dot2f(w1[8 + m],  (&q2.x)[m], a);
                    d = dot2f(w1[12 + m], (&q3.x)[m], d);
                }
                float z = fmaxf(bin_r + pxor1(a + d), 0.f);
                if (kh == 0) ((_Float16*)zAu)[c] = (_Float16)z;
            }
            __syncthreads();

            // ---- phase 2: G2 zA -> zB (interleaved LDS weights) ----
            {
                const uint32_t* zp = zAu + kh * 32;
                float a = 0.f, d = 0.f;
                #pragma unroll
                for (int j = 0; j < 8; ++j) {
                    uint4 wv = *reinterpret_cast<const uint4*>(&w2s[(j * 256 + t) * 4]);
                    uint4 zz = *reinterpret_cast<const uint4*>(zp + 4 * j);
                    a = dot2f(wv.x, zz.x, a); d = dot2f(wv.y, zz.y, d);
                    a = dot2f(wv.z, zz.z, a); d = dot2f(wv.w, zz.w, d);
                }
                float z = fmaxf(bh1_r + pxor1(a + d), 0.f);
                if (kh == 0) ((_Float16*)zBu)[c] = (_Float16)z;
            }
            __syncthreads();

            // ---- phase 3: G3 zB -> zA (interleaved LDS weights) ----
            {
                const uint32_t* zp = zBu + kh * 32;
                float a = 0.f, d = 0.f;
                #pragma unroll
                for (int j = 0; j < 8; ++j) {
                    uint4 wv = *reinterpret_cast<const uint4*>(&w3s[(j * 256 + t) * 4]);
                    uint4 zz = *reinterpret_cast<const uint4*>(zp + 4 * j);
                    a = dot2f(wv.x, zz.x, a); d = dot2f(wv.y, zz.y, d);
                    a = dot2f(wv.z, zz.z, a); d = dot2f(wv.w, zz.w, d);
                }
                float z = fmaxf(bh2_r + pxor1(a + d), 0.f);
                if (kh == 0) ((_Float16*)zAu)[c] = (_Float16)z;
            }
            __syncthreads();

            // ---- phase 4: G4 (3 A-cols, w4 in regs) + einsum + RK4 ----
            {
                const uint32_t* zp = zAu + kh * 32;
                uint4 z0 = *reinterpret_cast<const uint4*>(zp);
                uint4 z1 = *reinterpret_cast<const uint4*>(zp + 4);
                uint4 z2 = *reinterpret_cast<const uint4*>(zp + 8);
                uint4 z3 = *reinterpret_cast<const uint4*>(zp + 12);
                float av0 = 0.f, av1 = 0.f, av2 = 0.f;
                #pragma unroll
                for (int m = 0; m < 4; ++m) {
                    uint32_t y0 = (&z0.x)[m], y1 = (&z1.x)[m], y2 = (&z2.x)[m], y3 = (&z3.x)[m];
                    av0 = dot2f(w4[m],      y0, av0); av0 = dot2f(w4[4 + m],  y1, av0);
                    av0 = dot2f(w4[8 + m],  y2, av0); av0 = dot2f(w4[12 + m], y3, av0);
                    av1 = dot2f(w4[32 + m], y0, av1); av1 = dot2f(w4[36 + m], y1, av1);
                    av1 = dot2f(w4[40 + m], y2, av1); av1 = dot2f(w4[44 + m], y3, av1);
                    av2 = dot2f(w4[64 + m], y0, av2); av2 = dot2f(w4[68 + m], y1, av2);
                    av2 = dot2f(w4[72 + m], y2, av2); av2 = dot2f(w4[76 + m], y3, av2);
                }
                uint4 z4 = *reinterpret_cast<const uint4*>(zp + 16);
                uint4 z5 = *reinterpret_cast<const uint4*>(zp + 20);
                uint4 z6 = *reinterpret_cast<const uint4*>(zp + 24);
                uint4 z7 = *reinterpret_cast<const uint4*>(zp + 28);
                #pragma unroll
                for (int m = 0; m < 4; ++m) {
                    uint32_t y4 = (&z4.x)[m], y5 = (&z5.x)[m], y6 = (&z6.x)[m], y7 = (&z7.x)[m];
                    av0 = dot2f(w4[16 + m], y4, av0); av0 = dot2f(w4[20 + m], y5, av0);
                    av0 = dot2f(w4[24 + m], y6, av0); av0 = dot2f(w4[28 + m], y7, av0);
                    av1 = dot2f(w4[48 + m], y4, av1); av1 = dot2f(w4[52 + m], y5, av1);
                    av1 = dot2f(w4[56 + m], y6, av1); av1 = dot2f(w4[60 + m], y7, av1);
                    av2 = dot2f(w4[80 + m], y4, av2); av2 = dot2f(w4[84 + m], y5, av2);
                    av2 = dot2f(w4[88 + m], y6, av2); av2 = dot2f(w4[92 + m], y7, av2);
                }
                av0 = pxor1(av0); av1 = pxor1(av1); av2 = pxor1(av2);
                float kvp = tanh_fast(bo[0] + av0) * dxr[0]
                          + tanh_fast(bo[1] + av1) * dxr[1]
                          + tanh_fast(bo[2] + av2) * dxr[2];
                float kv = pxor2(kvp);          // row pair (c, c^1) -> full row sum

                hacc += ((s4 == 1 || s4 == 2) ? 2.0f : 1.0f) * kv;
                float hs;
                if (s4 < 3) {
                    hs = h_reg + ((s4 == 2) ? 1.0f : 0.5f) * kv;
                } else {
                    h_reg += hacc * (1.0f / 6.0f);
                    hacc = 0.f;
                    hs = h_reg;
                }
                if (wrt) {
                    ((_Float16*)hinu)[r_own] = (_Float16)hs;
                    if (s4 == 3) hbuf[r_own] = h_reg;
                }
            }
            // dX for step+1 (read at next step's s4==0, after the barrier below)
            if (s4 == 3 && step + 2 < T_ && t < IN_) {
                dxs[t] = xb - xa;
                xa = xb;
                if (step + 3 < T_) xb = x[xbase + (size_t)(step + 3) * IN_ + t];
            }
            __syncthreads();
        }
    }

    OUT_STAGE(T_ - 1)
#undef OUT_STAGE
}

} // namespace

extern "C" void kernel_launch(void* const* d_in, const int* in_sizes, int n_in,
                              void* d_out, int out_size, void* d_ws, size_t ws_size,
                              hipStream_t stream) {
    const float* x      = (const float*)d_in[0];
    const float* W_init = (const float*)d_in[1];
    const float* b_init = (const float*)d_in[2];
    const float* W_in   = (const float*)d_in[3];
    const float* b_in   = (const float*)d_in[4];
    const float* W_h1   = (const float*)d_in[5];
    const float* b_h1   = (const float*)d_in[6];
    const float* W_h2   = (const float*)d_in[7];
    const float* b_h2   = (const float*)d_in[8];
    const float* W_out  = (const float*)d_in[9];
    const float* b_out  = (const float*)d_in[10];
    const float* W_fin  = (const float*)d_in[11];
    const float* b_fin  = (const float*)d_in[12];
    float* out = (float*)d_out;

    cde_kernel<<<dim3(B_), dim3(256), 0, stream>>>(
        x, W_init, b_init, W_in, b_in, W_h1, b_h1, W_h2, b_h2,
        W_out, b_out, W_fin, b_fin, out);
}